// Round 1
// baseline (315.126 us; speedup 1.0000x reference)
//
#include <hip/hip_runtime.h>
#include <math.h>

#define GAMMA 9.6f
#define BETA  0.83f
#define LAMDA 10.0f
#define B_ 1024
#define D_ 512
#define C_ 10000

// ---- ws layout (bytes) ----
// 0      : inv_x   [1024] f32
// 4096   : inv_w   [10000] f32
// 44096  : s_u     [1024] u32   (encoded max-similarity per row)
// 48192  : sum_loss[1] f32
#define WS_INVX 0
#define WS_INVW 4096
#define WS_SU   44096
#define WS_SUM  48192

__device__ __forceinline__ unsigned enc_f(float f) {
    unsigned i = __float_as_uint(f);
    return (i & 0x80000000u) ? ~i : (i | 0x80000000u);
}
__device__ __forceinline__ float dec_f(unsigned u) {
    return (u & 0x80000000u) ? __uint_as_float(u ^ 0x80000000u)
                             : __uint_as_float(~u);
}
__device__ __forceinline__ float softplus_f(float x) {
    return (x > 30.f) ? x : log1pf(expf(x));
}

// ---------------- init ----------------
__global__ void init_kernel(unsigned* s_u, float* sum_loss) {
    int t = threadIdx.x;
    s_u[t] = 0u;                 // below enc(-1.0): safe identity for max
    if (t == 0) *sum_loss = 0.f;
}

// ---------------- row norms ----------------
// one block (128 thr) per row; rows 0..1023 -> input, 1024.. -> weight
__global__ __launch_bounds__(128) void norm_kernel(
    const float* __restrict__ input, const float* __restrict__ weight,
    float* __restrict__ inv_x, float* __restrict__ inv_w) {
    int row = blockIdx.x;
    int tid = threadIdx.x;
    const float* src = (row < B_) ? (input + (size_t)row * D_)
                                  : (weight + (size_t)(row - B_) * D_);
    float4 v = *(const float4*)(src + tid * 4);
    float ss = v.x * v.x + v.y * v.y + v.z * v.z + v.w * v.w;
    #pragma unroll
    for (int o = 32; o > 0; o >>= 1) ss += __shfl_xor(ss, o, 64);
    __shared__ float red[2];
    if ((tid & 63) == 0) red[tid >> 6] = ss;
    __syncthreads();
    if (tid == 0) {
        float s = red[0] + red[1];
        float inv = 1.0f / fmaxf(sqrtf(s), 1e-12f);
        if (row < B_) inv_x[row] = inv;
        else          inv_w[row - B_] = inv;
    }
}

// ---------------- fused GEMM ----------------
// virtual A: rows 0..1023 = x (normalized), rows 1024..2047 = w[label[r]] (normalized)
// B = w (normalized), N = 10000, K = 512
// M-tiles 0..7 write fea; tiles 8..15 do clip/diag-zero/row-max -> atomicMax(s_u)
#define BM 128
#define BN 128
#define BK 16

__global__ __launch_bounds__(256) void gemm_kernel(
    const float* __restrict__ x, const float* __restrict__ w,
    const int* __restrict__ label,
    const float* __restrict__ inv_x, const float* __restrict__ inv_w,
    float* __restrict__ fea, unsigned* __restrict__ s_u) {
    __shared__ float As[BK][BM];
    __shared__ float Bs[BK][BN];
    const int tid = threadIdx.x;
    const int n0 = blockIdx.x * BN;
    const int m0 = blockIdx.y * BM;
    const int tx = tid & 15;       // col group
    const int ty = tid >> 4;       // row group
    const int lm = tid >> 2;       // 0..63 : tile row for loads
    const int lk4 = tid & 3;       // 0..3  : which float4 along K

    // per-thread source rows (2 for A, 2 for B)
    const float* aptr[2]; float ascale[2];
    const float* bptr[2]; float bscale[2];
    #pragma unroll
    for (int q = 0; q < 2; q++) {
        int m = m0 + lm + q * 64;
        if (m < B_) { aptr[q] = x + (size_t)m * D_; ascale[q] = inv_x[m]; }
        else { int l = label[m - B_]; aptr[q] = w + (size_t)l * D_; ascale[q] = inv_w[l]; }
        int n = n0 + lm + q * 64;
        int nn = (n < C_) ? n : 0;
        bptr[q] = w + (size_t)nn * D_;
        bscale[q] = (n < C_) ? inv_w[nn] : 0.f;
    }

    float acc[8][8];
    #pragma unroll
    for (int i = 0; i < 8; i++)
        #pragma unroll
        for (int j = 0; j < 8; j++) acc[i][j] = 0.f;

    for (int kt = 0; kt < D_; kt += BK) {
        #pragma unroll
        for (int q = 0; q < 2; q++) {
            int m = lm + q * 64;
            float4 a = *(const float4*)(aptr[q] + kt + lk4 * 4);
            As[lk4 * 4 + 0][m] = a.x * ascale[q];
            As[lk4 * 4 + 1][m] = a.y * ascale[q];
            As[lk4 * 4 + 2][m] = a.z * ascale[q];
            As[lk4 * 4 + 3][m] = a.w * ascale[q];
            float4 b = *(const float4*)(bptr[q] + kt + lk4 * 4);
            Bs[lk4 * 4 + 0][m] = b.x * bscale[q];
            Bs[lk4 * 4 + 1][m] = b.y * bscale[q];
            Bs[lk4 * 4 + 2][m] = b.z * bscale[q];
            Bs[lk4 * 4 + 3][m] = b.w * bscale[q];
        }
        __syncthreads();
        #pragma unroll
        for (int k = 0; k < BK; k++) {
            float a[8], b[8];
            *(float4*)&a[0] = *(const float4*)&As[k][ty * 8];
            *(float4*)&a[4] = *(const float4*)&As[k][ty * 8 + 4];
            *(float4*)&b[0] = *(const float4*)&Bs[k][tx * 8];
            *(float4*)&b[4] = *(const float4*)&Bs[k][tx * 8 + 4];
            #pragma unroll
            for (int i = 0; i < 8; i++)
                #pragma unroll
                for (int j = 0; j < 8; j++)
                    acc[i][j] = fmaf(a[i], b[j], acc[i][j]);
        }
        __syncthreads();
    }

    if (m0 < B_) {
        // fea rows
        #pragma unroll
        for (int i = 0; i < 8; i++) {
            int m = m0 + ty * 8 + i;
            #pragma unroll
            for (int j = 0; j < 8; j++) {
                int n = n0 + tx * 8 + j;
                if (n < C_) fea[(size_t)m * C_ + n] = acc[i][j];
            }
        }
    } else {
        // w[label] rows: clip, zero diagonal, row max
        #pragma unroll
        for (int i = 0; i < 8; i++) {
            int r = m0 - B_ + ty * 8 + i;
            int l = label[r];
            float vmax = -2.f;
            #pragma unroll
            for (int j = 0; j < 8; j++) {
                int n = n0 + tx * 8 + j;
                float v = fminf(fmaxf(acc[i][j], -1.f), 1.f);
                if (n == l) v = 0.f;         // diagonal zeroed (not excluded)
                if (n < C_) vmax = fmaxf(vmax, v);
            }
            // reduce across the 16 tx lanes (aligned 16-lane groups in wave)
            #pragma unroll
            for (int o = 8; o > 0; o >>= 1)
                vmax = fmaxf(vmax, __shfl_xor(vmax, o, 64));
            if (tx == 0) atomicMax(s_u + r, enc_f(vmax));
        }
    }
}

// ---------------- per-row logsumexp + softplus ----------------
__global__ __launch_bounds__(256) void row_lse_kernel(
    const float* __restrict__ fea, const float* __restrict__ cw,
    const int* __restrict__ label, float* __restrict__ sum_loss) {
    int row = blockIdx.x;
    int tid = threadIdx.x;
    const float* fr = fea + (size_t)row * C_;
    int l = label[row];
    float m = -1e30f, s = 0.f;
    for (int t = tid; t < C_ / 4; t += 256) {
        float4 f = *(const float4*)(fr + t * 4);
        float4 c = *(const float4*)(cw + t * 4);
        float vals[4] = { f.x + BETA * c.x, f.y + BETA * c.y,
                          f.z + BETA * c.z, f.w + BETA * c.w };
        int j0 = t * 4;
        #pragma unroll
        for (int e = 0; e < 4; e++) {
            if (j0 + e == l) continue;       // masked positive column
            float logit = GAMMA * vals[e];
            if (logit <= m) s += expf(logit - m);
            else { s = s * expf(m - logit) + 1.f; m = logit; }
        }
    }
    // wave reduce (m,s)
    #pragma unroll
    for (int o = 32; o > 0; o >>= 1) {
        float om = __shfl_xor(m, o, 64);
        float os = __shfl_xor(s, o, 64);
        float nm = fmaxf(m, om);
        s = s * expf(m - nm) + os * expf(om - nm);
        m = nm;
    }
    __shared__ float red_m[4], red_s[4];
    if ((tid & 63) == 0) { red_m[tid >> 6] = m; red_s[tid >> 6] = s; }
    __syncthreads();
    if (tid == 0) {
        float M = red_m[0], S = red_s[0];
        #pragma unroll
        for (int wv = 1; wv < 4; wv++) {
            float om = red_m[wv], os = red_s[wv];
            float nm = fmaxf(M, om);
            S = S * expf(M - nm) + os * expf(om - nm);
            M = nm;
        }
        float sp = fr[l];                       // fea[row, label]
        float lse = M + logf(S) - GAMMA * sp;
        atomicAdd(sum_loss, softplus_f(lse));
    }
}

// ---------------- final scalar ----------------
__global__ __launch_bounds__(1024) void final_kernel(
    const unsigned* __restrict__ s_u, const float* __restrict__ sum_loss,
    float* __restrict__ out_loss) {
    int tid = threadIdx.x;
    float s = dec_f(s_u[tid]);
    #pragma unroll
    for (int o = 32; o > 0; o >>= 1) s += __shfl_xor(s, o, 64);
    __shared__ float red[16];
    if ((tid & 63) == 0) red[tid >> 6] = s;
    __syncthreads();
    if (tid == 0) {
        float tot = 0.f;
        #pragma unroll
        for (int wv = 0; wv < 16; wv++) tot += red[wv];
        float loss_w = softplus_f(tot / (float)B_ + 0.5f);
        *out_loss = *sum_loss / (float)B_ + LAMDA * loss_w;
    }
}

extern "C" void kernel_launch(void* const* d_in, const int* in_sizes, int n_in,
                              void* d_out, int out_size, void* d_ws, size_t ws_size,
                              hipStream_t stream) {
    const float* input  = (const float*)d_in[0];
    const float* weight = (const float*)d_in[1];
    const float* cw     = (const float*)d_in[2];
    const int*   label  = (const int*)d_in[3];
    float* out = (float*)d_out;

    char* ws = (char*)d_ws;
    float*    inv_x    = (float*)(ws + WS_INVX);
    float*    inv_w    = (float*)(ws + WS_INVW);
    unsigned* s_u      = (unsigned*)(ws + WS_SU);
    float*    sum_loss = (float*)(ws + WS_SUM);

    init_kernel<<<1, 1024, 0, stream>>>(s_u, sum_loss);
    norm_kernel<<<B_ + C_, 128, 0, stream>>>(input, weight, inv_x, inv_w);

    dim3 grid_g((C_ + BN - 1) / BN, (2 * B_) / BM);
    gemm_kernel<<<grid_g, 256, 0, stream>>>(input, weight, label, inv_x, inv_w,
                                            out, s_u);

    row_lse_kernel<<<B_, 256, 0, stream>>>(out, cw, label, sum_loss);
    final_kernel<<<1, 1024, 0, stream>>>(s_u, sum_loss, out + (size_t)B_ * C_);
}

// Round 2
// 110.492 us; speedup vs baseline: 2.8520x; 2.8520x over previous
//
#include <hip/hip_runtime.h>
#include <math.h>

#define GAMMA 9.6f
#define BETA  0.83f
#define LAMDA 10.0f
#define B_ 1024
#define D_ 512
#define C_ 10000

// ---- ws layout (bytes) ----
// 0        : xb  [1024*512]  bf16 (normalized input rows)
// 1048576  : wb  [10000*512] bf16 (normalized weight rows)
// 11288576 : s_u [1024] u32 (encoded max-similarity per row)
// 11292672 : sum_loss [1] f32
#define WS_XB   0
#define WS_WB   1048576
#define WS_SU   11288576
#define WS_SUM  11292672

typedef __attribute__((ext_vector_type(8))) short short8;
typedef __attribute__((ext_vector_type(4))) float floatx4;

__device__ __forceinline__ unsigned enc_f(float f) {
    unsigned i = __float_as_uint(f);
    return (i & 0x80000000u) ? ~i : (i | 0x80000000u);
}
__device__ __forceinline__ float dec_f(unsigned u) {
    return (u & 0x80000000u) ? __uint_as_float(u ^ 0x80000000u)
                             : __uint_as_float(~u);
}
__device__ __forceinline__ float softplus_f(float x) {
    return (x > 30.f) ? x : log1pf(expf(x));
}
__device__ __forceinline__ unsigned short f2bf_rne(float f) {
    unsigned u = __float_as_uint(f);
    u += 0x7FFFu + ((u >> 16) & 1u);
    return (unsigned short)(u >> 16);
}

// ---------------- init ----------------
__global__ void init_kernel(unsigned* s_u, float* sum_loss) {
    int t = threadIdx.x;
    s_u[t] = 0u;                 // below enc(-1.0): safe identity for max
    if (t == 0) *sum_loss = 0.f;
}

// ---------------- normalize + convert to bf16 ----------------
// one block (128 thr) per row; rows 0..1023 -> input->xb, 1024.. -> weight->wb
__global__ __launch_bounds__(128) void normcvt_kernel(
    const float* __restrict__ input, const float* __restrict__ weight,
    unsigned short* __restrict__ xb, unsigned short* __restrict__ wb) {
    int row = blockIdx.x;
    int tid = threadIdx.x;
    const float* src = (row < B_) ? (input + (size_t)row * D_)
                                  : (weight + (size_t)(row - B_) * D_);
    float4 v = *(const float4*)(src + tid * 4);
    float ss = v.x * v.x + v.y * v.y + v.z * v.z + v.w * v.w;
    #pragma unroll
    for (int o = 32; o > 0; o >>= 1) ss += __shfl_xor(ss, o, 64);
    __shared__ float red[2];
    if ((tid & 63) == 0) red[tid >> 6] = ss;
    __syncthreads();
    float inv = 1.0f / fmaxf(sqrtf(red[0] + red[1]), 1e-12f);
    unsigned short* dst = (row < B_) ? (xb + (size_t)row * D_)
                                     : (wb + (size_t)(row - B_) * D_);
    ushort4 o4;
    o4.x = f2bf_rne(v.x * inv);
    o4.y = f2bf_rne(v.y * inv);
    o4.z = f2bf_rne(v.z * inv);
    o4.w = f2bf_rne(v.w * inv);
    *(ushort4*)(dst + tid * 4) = o4;
}

// ---------------- fused bf16 MFMA GEMM ----------------
// virtual A: rows 0..1023 = xb, rows 1024..2047 = wb[label[r]]
// B = wb, N = 10000, K = 512
// M-tiles 0..7 write fea; tiles 8..15 clip/diag-zero/row-max -> atomicMax(s_u)
#define BM 128
#define BN 128
#define BK 32

__global__ __launch_bounds__(256) void mfma_gemm_kernel(
    const unsigned short* __restrict__ xb, const unsigned short* __restrict__ wb,
    const int* __restrict__ label,
    float* __restrict__ fea, unsigned* __restrict__ s_u) {
    __shared__ __align__(16) unsigned short As[BM * BK];  // [row][k] row-major
    __shared__ __align__(16) unsigned short Bs[BN * BK];
    __shared__ int lbl[BM];

    const int tid = threadIdx.x;
    const int n0 = blockIdx.x * BN;
    const int m0 = blockIdx.y * BM;
    const bool feaTile = (m0 < B_);

    // staging sources: thread t covers tile-row (t>>2)+q*64, k-chunk (t&3)*8
    const int arow = tid >> 2;          // 0..63
    const int kc8 = (tid & 3) * 8;      // bf16 element offset along K
    const unsigned short* asrc[2];
    const unsigned short* bsrc[2];
    #pragma unroll
    for (int q = 0; q < 2; q++) {
        int rm = m0 + arow + q * 64;
        const unsigned short* ab;
        if (rm < B_) ab = xb + (size_t)rm * D_;
        else         ab = wb + (size_t)label[rm - B_] * D_;
        asrc[q] = ab + kc8;
        int rn = n0 + arow + q * 64;
        if (rn >= C_) rn = C_ - 1;
        bsrc[q] = wb + (size_t)rn * D_ + kc8;
    }
    if (!feaTile && tid < BM) lbl[tid] = label[m0 - B_ + tid];

    const int lane = tid & 63;
    const int wv = tid >> 6;            // wave 0..3 -> 2x2 of 64x64
    const int wr = (wv >> 1) * 64;
    const int wc = (wv & 1) * 64;
    const int l15 = lane & 15;
    const int hi = lane >> 4;           // 0..3

    floatx4 acc[4][4];
    #pragma unroll
    for (int i = 0; i < 4; i++)
        #pragma unroll
        for (int j = 0; j < 4; j++)
            acc[i][j] = (floatx4){0.f, 0.f, 0.f, 0.f};

    for (int kt = 0; kt < D_; kt += BK) {
        #pragma unroll
        for (int q = 0; q < 2; q++) {
            __builtin_amdgcn_global_load_lds(
                (const __attribute__((address_space(1))) void*)(asrc[q] + kt),
                (__attribute__((address_space(3))) void*)((char*)As + tid * 16 + q * 4096),
                16, 0, 0);
            __builtin_amdgcn_global_load_lds(
                (const __attribute__((address_space(1))) void*)(bsrc[q] + kt),
                (__attribute__((address_space(3))) void*)((char*)Bs + tid * 16 + q * 4096),
                16, 0, 0);
        }
        __syncthreads();
        short8 a[4], b[4];
        #pragma unroll
        for (int i = 0; i < 4; i++)
            a[i] = *(const short8*)&As[(wr + i * 16 + l15) * BK + hi * 8];
        #pragma unroll
        for (int j = 0; j < 4; j++)
            b[j] = *(const short8*)&Bs[(wc + j * 16 + l15) * BK + hi * 8];
        #pragma unroll
        for (int i = 0; i < 4; i++)
            #pragma unroll
            for (int j = 0; j < 4; j++)
                acc[i][j] = __builtin_amdgcn_mfma_f32_16x16x32_bf16(
                    a[i], b[j], acc[i][j], 0, 0, 0);
        __syncthreads();
    }

    if (feaTile) {
        #pragma unroll
        for (int i = 0; i < 4; i++) {
            int m = m0 + wr + i * 16 + hi * 4;
            #pragma unroll
            for (int j = 0; j < 4; j++) {
                int n = n0 + wc + j * 16 + l15;
                if (n < C_) {
                    float* dst = fea + (size_t)m * C_ + n;
                    #pragma unroll
                    for (int r = 0; r < 4; r++)
                        dst[(size_t)r * C_] = acc[i][j][r];
                }
            }
        }
    } else {
        #pragma unroll
        for (int i = 0; i < 4; i++) {
            #pragma unroll
            for (int r = 0; r < 4; r++) {
                int row = wr + i * 16 + hi * 4 + r;    // 0..127 in tile
                int l = lbl[row];
                float vmax = -2.f;
                #pragma unroll
                for (int j = 0; j < 4; j++) {
                    int n = n0 + wc + j * 16 + l15;
                    float v = fminf(fmaxf(acc[i][j][r], -1.f), 1.f);
                    if (n == l) v = 0.f;               // diagonal zeroed
                    if (n < C_) vmax = fmaxf(vmax, v);
                }
                #pragma unroll
                for (int o = 8; o > 0; o >>= 1)
                    vmax = fmaxf(vmax, __shfl_xor(vmax, o, 64));
                if (l15 == 0) atomicMax(s_u + (m0 - B_ + row), enc_f(vmax));
            }
        }
    }
}

// ---------------- per-row logsumexp + softplus ----------------
__global__ __launch_bounds__(256) void row_lse_kernel(
    const float* __restrict__ fea, const float* __restrict__ cw,
    const int* __restrict__ label, float* __restrict__ sum_loss) {
    int row = blockIdx.x;
    int tid = threadIdx.x;
    const float* fr = fea + (size_t)row * C_;
    int l = label[row];
    float m = -1e30f, s = 0.f;
    for (int t = tid; t < C_ / 4; t += 256) {
        float4 f = *(const float4*)(fr + t * 4);
        float4 c = *(const float4*)(cw + t * 4);
        float vals[4] = { f.x + BETA * c.x, f.y + BETA * c.y,
                          f.z + BETA * c.z, f.w + BETA * c.w };
        int j0 = t * 4;
        #pragma unroll
        for (int e = 0; e < 4; e++) {
            if (j0 + e == l) continue;       // masked positive column
            float logit = GAMMA * vals[e];
            if (logit <= m) s += expf(logit - m);
            else { s = s * expf(m - logit) + 1.f; m = logit; }
        }
    }
    #pragma unroll
    for (int o = 32; o > 0; o >>= 1) {
        float om = __shfl_xor(m, o, 64);
        float os = __shfl_xor(s, o, 64);
        float nm = fmaxf(m, om);
        s = s * expf(m - nm) + os * expf(om - nm);
        m = nm;
    }
    __shared__ float red_m[4], red_s[4];
    if ((tid & 63) == 0) { red_m[tid >> 6] = m; red_s[tid >> 6] = s; }
    __syncthreads();
    if (tid == 0) {
        float M = red_m[0], S = red_s[0];
        #pragma unroll
        for (int wv = 1; wv < 4; wv++) {
            float om = red_m[wv], os = red_s[wv];
            float nm = fmaxf(M, om);
            S = S * expf(M - nm) + os * expf(om - nm);
            M = nm;
        }
        float sp = fr[l];                       // fea[row, label]
        float lse = M + logf(S) - GAMMA * sp;
        atomicAdd(sum_loss, softplus_f(lse));
    }
}

// ---------------- final scalar ----------------
__global__ __launch_bounds__(1024) void final_kernel(
    const unsigned* __restrict__ s_u, const float* __restrict__ sum_loss,
    float* __restrict__ out_loss) {
    int tid = threadIdx.x;
    float s = dec_f(s_u[tid]);
    #pragma unroll
    for (int o = 32; o > 0; o >>= 1) s += __shfl_xor(s, o, 64);
    __shared__ float red[16];
    if ((tid & 63) == 0) red[tid >> 6] = s;
    __syncthreads();
    if (tid == 0) {
        float tot = 0.f;
        #pragma unroll
        for (int wv = 0; wv < 16; wv++) tot += red[wv];
        float loss_w = softplus_f(tot / (float)B_ + 0.5f);
        *out_loss = *sum_loss / (float)B_ + LAMDA * loss_w;
    }
}

extern "C" void kernel_launch(void* const* d_in, const int* in_sizes, int n_in,
                              void* d_out, int out_size, void* d_ws, size_t ws_size,
                              hipStream_t stream) {
    const float* input  = (const float*)d_in[0];
    const float* weight = (const float*)d_in[1];
    const float* cw     = (const float*)d_in[2];
    const int*   label  = (const int*)d_in[3];
    float* out = (float*)d_out;

    char* ws = (char*)d_ws;
    unsigned short* xb = (unsigned short*)(ws + WS_XB);
    unsigned short* wb = (unsigned short*)(ws + WS_WB);
    unsigned* s_u      = (unsigned*)(ws + WS_SU);
    float*    sum_loss = (float*)(ws + WS_SUM);

    init_kernel<<<1, 1024, 0, stream>>>(s_u, sum_loss);
    normcvt_kernel<<<B_ + C_, 128, 0, stream>>>(input, weight, xb, wb);

    dim3 grid_g((C_ + BN - 1) / BN, (2 * B_) / BM);
    mfma_gemm_kernel<<<grid_g, 256, 0, stream>>>(xb, wb, label, out, s_u);

    row_lse_kernel<<<B_, 256, 0, stream>>>(out, cw, label, sum_loss);
    final_kernel<<<1, 1024, 0, stream>>>(s_u, sum_loss, out + (size_t)B_ * C_);
}

// Round 3
// 81.330 us; speedup vs baseline: 3.8747x; 1.3586x over previous
//
#include <hip/hip_runtime.h>
#include <math.h>

#define GAMMA 9.6f
#define BETA  0.83f
#define LAMDA 10.0f
#define B_ 1024
#define D_ 512
#define C_ 10000

// ---- ws layout (bytes) ----
// 0        : xb  [1024*512]  bf16 (normalized input rows)
// 1048576  : wb  [10000*512] bf16 (normalized weight rows)
// 11288576 : s_u [1024] u32 (encoded max-similarity per row)
// 11292672 : sum_loss [1] f32
#define WS_XB   0
#define WS_WB   1048576
#define WS_SU   11288576
#define WS_SUM  11292672

typedef __attribute__((ext_vector_type(8))) short short8;
typedef __attribute__((ext_vector_type(4))) float floatx4;

__device__ __forceinline__ unsigned enc_f(float f) {
    unsigned i = __float_as_uint(f);
    return (i & 0x80000000u) ? ~i : (i | 0x80000000u);
}
__device__ __forceinline__ float dec_f(unsigned u) {
    return (u & 0x80000000u) ? __uint_as_float(u ^ 0x80000000u)
                             : __uint_as_float(~u);
}
__device__ __forceinline__ float softplus_f(float x) {
    return (x > 30.f) ? x : log1pf(expf(x));
}
__device__ __forceinline__ unsigned short f2bf_rne(float f) {
    unsigned u = __float_as_uint(f);
    u += 0x7FFFu + ((u >> 16) & 1u);
    return (unsigned short)(u >> 16);
}

// ---------------- normalize + convert to bf16 (+ fused init) ----------------
// one block (128 thr) per row; rows 0..1023 -> input->xb, 1024.. -> weight->wb
__global__ __launch_bounds__(128) void normcvt_kernel(
    const float* __restrict__ input, const float* __restrict__ weight,
    unsigned short* __restrict__ xb, unsigned short* __restrict__ wb,
    unsigned* __restrict__ s_u, float* __restrict__ sum_loss) {
    int row = blockIdx.x;
    int tid = threadIdx.x;
    // fused init: first 1024 blocks zero s_u; block 0 zeroes sum_loss
    if (row < B_ && tid == 0) s_u[row] = 0u;   // 0 < enc(-1): safe max identity
    if (row == 0 && tid == 1) *sum_loss = 0.f;

    const float* src = (row < B_) ? (input + (size_t)row * D_)
                                  : (weight + (size_t)(row - B_) * D_);
    float4 v = *(const float4*)(src + tid * 4);
    float ss = v.x * v.x + v.y * v.y + v.z * v.z + v.w * v.w;
    #pragma unroll
    for (int o = 32; o > 0; o >>= 1) ss += __shfl_xor(ss, o, 64);
    __shared__ float red[2];
    if ((tid & 63) == 0) red[tid >> 6] = ss;
    __syncthreads();
    float inv = 1.0f / fmaxf(sqrtf(red[0] + red[1]), 1e-12f);
    unsigned short* dst = (row < B_) ? (xb + (size_t)row * D_)
                                     : (wb + (size_t)(row - B_) * D_);
    ushort4 o4;
    o4.x = f2bf_rne(v.x * inv);
    o4.y = f2bf_rne(v.y * inv);
    o4.z = f2bf_rne(v.z * inv);
    o4.w = f2bf_rne(v.w * inv);
    *(ushort4*)(dst + tid * 4) = o4;
}

// ---------------- fused bf16 MFMA GEMM, 2-phase prefetch ----------------
// virtual A: rows 0..1023 = xb, rows 1024..2047 = wb[label[r]]
// B = wb, N = 10000, K = 512
// m-tiles 0..7 write fea; tiles 8..15 clip/diag-zero/row-max -> atomicMax(s_u)
#define BM 128
#define BN 128
#define BK 32
#define NTILE_M 16
#define NTILE_N 79
#define NWG (NTILE_M * NTILE_N)   // 1264 = 8 * 158

__global__ __launch_bounds__(256) void mfma_gemm_kernel(
    const unsigned short* __restrict__ xb, const unsigned short* __restrict__ wb,
    const int* __restrict__ label,
    float* __restrict__ fea, unsigned* __restrict__ s_u) {
    __shared__ __align__(16) unsigned short As[2][BM * BK];
    __shared__ __align__(16) unsigned short Bs[2][BM * BK];
    __shared__ int lbl[BM];

    const int tid = threadIdx.x;
    // bijective XCD swizzle: 1264 % 8 == 0; XCD c gets orig in [c*158,(c+1)*158)
    // orig: m-tile fastest -> 16 consecutive blocks on one XCD share a B-panel
    const int orig = (blockIdx.x & 7) * (NWG / 8) + (blockIdx.x >> 3);
    const int m0 = (orig & 15) * BM;
    const int n0 = (orig >> 4) * BN;
    const bool feaTile = (m0 < B_);

    // staging sources: thread t covers tile-row (t>>2)+q*64, k-chunk (t&3)*8
    const int arow = tid >> 2;          // 0..63
    const int kc8 = (tid & 3) * 8;      // bf16 element offset along K
    const unsigned short* asrc[2];
    const unsigned short* bsrc[2];
    #pragma unroll
    for (int q = 0; q < 2; q++) {
        int rm = m0 + arow + q * 64;
        const unsigned short* ab;
        if (rm < B_) ab = xb + (size_t)rm * D_;
        else         ab = wb + (size_t)label[rm - B_] * D_;
        asrc[q] = ab + kc8;
        int rn = n0 + arow + q * 64;
        if (rn >= C_) rn = C_ - 1;
        bsrc[q] = wb + (size_t)rn * D_ + kc8;
    }
    if (!feaTile && tid < BM) lbl[tid] = label[m0 - B_ + tid];

    const int lane = tid & 63;
    const int wv = tid >> 6;            // wave 0..3 -> 2x2 of 64x64
    const int wr = (wv >> 1) * 64;
    const int wc = (wv & 1) * 64;
    const int l15 = lane & 15;
    const int hi = lane >> 4;           // 0..3

    floatx4 acc[4][4];
    #pragma unroll
    for (int i = 0; i < 4; i++)
        #pragma unroll
        for (int j = 0; j < 4; j++)
            acc[i][j] = (floatx4){0.f, 0.f, 0.f, 0.f};

#define STAGE(buf, kt)                                                         \
    {                                                                          \
        _Pragma("unroll")                                                      \
        for (int q = 0; q < 2; q++) {                                          \
            __builtin_amdgcn_global_load_lds(                                  \
                (const __attribute__((address_space(1))) void*)(asrc[q] + (kt)),\
                (__attribute__((address_space(3))) void*)((char*)&As[buf][0] + tid * 16 + q * 4096), \
                16, 0, 0);                                                     \
            __builtin_amdgcn_global_load_lds(                                  \
                (const __attribute__((address_space(1))) void*)(bsrc[q] + (kt)),\
                (__attribute__((address_space(3))) void*)((char*)&Bs[buf][0] + tid * 16 + q * 4096), \
                16, 0, 0);                                                     \
        }                                                                      \
    }

    // prologue: stage K-step 0 into buf 0
    STAGE(0, 0);
    __syncthreads();

    int cur = 0;
    for (int t = 0; t < D_ / BK; ++t) {
        int ktn = (t + 1) * BK;
        if (ktn < D_) STAGE(cur ^ 1, ktn);   // prefetch next step (in flight during compute)
        short8 a[4], b[4];
        #pragma unroll
        for (int i = 0; i < 4; i++)
            a[i] = *(const short8*)&As[cur][(wr + i * 16 + l15) * BK + hi * 8];
        #pragma unroll
        for (int j = 0; j < 4; j++)
            b[j] = *(const short8*)&Bs[cur][(wc + j * 16 + l15) * BK + hi * 8];
        #pragma unroll
        for (int i = 0; i < 4; i++)
            #pragma unroll
            for (int j = 0; j < 4; j++)
                acc[i][j] = __builtin_amdgcn_mfma_f32_16x16x32_bf16(
                    a[i], b[j], acc[i][j], 0, 0, 0);
        __syncthreads();   // drains vmcnt(0): next-step stage is complete; buf swap safe
        cur ^= 1;
    }

    if (feaTile) {
        #pragma unroll
        for (int i = 0; i < 4; i++) {
            int m = m0 + wr + i * 16 + hi * 4;
            #pragma unroll
            for (int j = 0; j < 4; j++) {
                int n = n0 + wc + j * 16 + l15;
                if (n < C_) {
                    float* dst = fea + (size_t)m * C_ + n;
                    #pragma unroll
                    for (int r = 0; r < 4; r++)
                        dst[(size_t)r * C_] = acc[i][j][r];
                }
            }
        }
    } else {
        #pragma unroll
        for (int i = 0; i < 4; i++) {
            #pragma unroll
            for (int r = 0; r < 4; r++) {
                int row = wr + i * 16 + hi * 4 + r;    // 0..127 in tile
                int l = lbl[row];
                float vmax = -2.f;
                #pragma unroll
                for (int j = 0; j < 4; j++) {
                    int n = n0 + wc + j * 16 + l15;
                    float v = fminf(fmaxf(acc[i][j][r], -1.f), 1.f);
                    if (n == l) v = 0.f;               // diagonal zeroed
                    if (n < C_) vmax = fmaxf(vmax, v);
                }
                #pragma unroll
                for (int o = 8; o > 0; o >>= 1)
                    vmax = fmaxf(vmax, __shfl_xor(vmax, o, 64));
                if (l15 == 0) atomicMax(s_u + (m0 - B_ + row), enc_f(vmax));
            }
        }
    }
}

// ---------------- per-row logsumexp + softplus ----------------
__global__ __launch_bounds__(256) void row_lse_kernel(
    const float* __restrict__ fea, const float* __restrict__ cw,
    const int* __restrict__ label, float* __restrict__ sum_loss) {
    int row = blockIdx.x;
    int tid = threadIdx.x;
    const float* fr = fea + (size_t)row * C_;
    int l = label[row];
    float m = -1e30f, s = 0.f;
    for (int t = tid; t < C_ / 4; t += 256) {
        float4 f = *(const float4*)(fr + t * 4);
        float4 c = *(const float4*)(cw + t * 4);
        float vals[4] = { f.x + BETA * c.x, f.y + BETA * c.y,
                          f.z + BETA * c.z, f.w + BETA * c.w };
        int j0 = t * 4;
        #pragma unroll
        for (int e = 0; e < 4; e++) {
            if (j0 + e == l) continue;       // masked positive column
            float logit = GAMMA * vals[e];
            if (logit <= m) s += expf(logit - m);
            else { s = s * expf(m - logit) + 1.f; m = logit; }
        }
    }
    #pragma unroll
    for (int o = 32; o > 0; o >>= 1) {
        float om = __shfl_xor(m, o, 64);
        float os = __shfl_xor(s, o, 64);
        float nm = fmaxf(m, om);
        s = s * expf(m - nm) + os * expf(om - nm);
        m = nm;
    }
    __shared__ float red_m[4], red_s[4];
    if ((tid & 63) == 0) { red_m[tid >> 6] = m; red_s[tid >> 6] = s; }
    __syncthreads();
    if (tid == 0) {
        float M = red_m[0], S = red_s[0];
        #pragma unroll
        for (int wv = 1; wv < 4; wv++) {
            float om = red_m[wv], os = red_s[wv];
            float nm = fmaxf(M, om);
            S = S * expf(M - nm) + os * expf(om - nm);
            M = nm;
        }
        float sp = fr[l];                       // fea[row, label]
        float lse = M + logf(S) - GAMMA * sp;
        atomicAdd(sum_loss, softplus_f(lse));
    }
}

// ---------------- final scalar ----------------
__global__ __launch_bounds__(1024) void final_kernel(
    const unsigned* __restrict__ s_u, const float* __restrict__ sum_loss,
    float* __restrict__ out_loss) {
    int tid = threadIdx.x;
    float s = dec_f(s_u[tid]);
    #pragma unroll
    for (int o = 32; o > 0; o >>= 1) s += __shfl_xor(s, o, 64);
    __shared__ float red[16];
    if ((tid & 63) == 0) red[tid >> 6] = s;
    __syncthreads();
    if (tid == 0) {
        float tot = 0.f;
        #pragma unroll
        for (int wv = 0; wv < 16; wv++) tot += red[wv];
        float loss_w = softplus_f(tot / (float)B_ + 0.5f);
        *out_loss = *sum_loss / (float)B_ + LAMDA * loss_w;
    }
}

extern "C" void kernel_launch(void* const* d_in, const int* in_sizes, int n_in,
                              void* d_out, int out_size, void* d_ws, size_t ws_size,
                              hipStream_t stream) {
    const float* input  = (const float*)d_in[0];
    const float* weight = (const float*)d_in[1];
    const float* cw     = (const float*)d_in[2];
    const int*   label  = (const int*)d_in[3];
    float* out = (float*)d_out;

    char* ws = (char*)d_ws;
    unsigned short* xb = (unsigned short*)(ws + WS_XB);
    unsigned short* wb = (unsigned short*)(ws + WS_WB);
    unsigned* s_u      = (unsigned*)(ws + WS_SU);
    float*    sum_loss = (float*)(ws + WS_SUM);

    normcvt_kernel<<<B_ + C_, 128, 0, stream>>>(input, weight, xb, wb, s_u, sum_loss);

    mfma_gemm_kernel<<<NWG, 256, 0, stream>>>(xb, wb, label, out, s_u);

    row_lse_kernel<<<B_, 256, 0, stream>>>(out, cw, label, sum_loss);
    final_kernel<<<1, 1024, 0, stream>>>(s_u, sum_loss, out + (size_t)B_ * C_);
}

// Round 4
// 80.815 us; speedup vs baseline: 3.8993x; 1.0064x over previous
//
#include <hip/hip_runtime.h>
#include <math.h>

#define GAMMA 9.6f
#define BETA  0.83f
#define LAMDA 10.0f
#define B_ 1024
#define D_ 512
#define C_ 10000

// ---- ws layout (bytes) ----
#define WS_XB   0
#define WS_WB   1048576
#define WS_SU   11288576
#define WS_SUM  11292672

typedef __attribute__((ext_vector_type(8))) short short8;
typedef __attribute__((ext_vector_type(4))) float floatx4;

__device__ __forceinline__ unsigned enc_f(float f) {
    unsigned i = __float_as_uint(f);
    return (i & 0x80000000u) ? ~i : (i | 0x80000000u);
}
__device__ __forceinline__ float dec_f(unsigned u) {
    return (u & 0x80000000u) ? __uint_as_float(u ^ 0x80000000u)
                             : __uint_as_float(~u);
}
__device__ __forceinline__ float softplus_f(float x) {
    return (x > 30.f) ? x : log1pf(expf(x));
}
__device__ __forceinline__ unsigned short f2bf_rne(float f) {
    unsigned u = __float_as_uint(f);
    u += 0x7FFFu + ((u >> 16) & 1u);
    return (unsigned short)(u >> 16);
}

// ---------------- normalize + convert to bf16 (+ fused init) ----------------
__global__ __launch_bounds__(128) void normcvt_kernel(
    const float* __restrict__ input, const float* __restrict__ weight,
    unsigned short* __restrict__ xb, unsigned short* __restrict__ wb,
    unsigned* __restrict__ s_u, float* __restrict__ sum_loss) {
    int row = blockIdx.x;
    int tid = threadIdx.x;
    if (row < B_ && tid == 0) s_u[row] = 0u;   // 0 < enc(-1): safe max identity
    if (row == 0 && tid == 1) *sum_loss = 0.f;

    const float* src = (row < B_) ? (input + (size_t)row * D_)
                                  : (weight + (size_t)(row - B_) * D_);
    float4 v = *(const float4*)(src + tid * 4);
    float ss = v.x * v.x + v.y * v.y + v.z * v.z + v.w * v.w;
    #pragma unroll
    for (int o = 32; o > 0; o >>= 1) ss += __shfl_xor(ss, o, 64);
    __shared__ float red[2];
    if ((tid & 63) == 0) red[tid >> 6] = ss;
    __syncthreads();
    float inv = 1.0f / fmaxf(sqrtf(red[0] + red[1]), 1e-12f);
    unsigned short* dst = (row < B_) ? (xb + (size_t)row * D_)
                                     : (wb + (size_t)(row - B_) * D_);
    ushort4 o4;
    o4.x = f2bf_rne(v.x * inv);
    o4.y = f2bf_rne(v.y * inv);
    o4.z = f2bf_rne(v.z * inv);
    o4.w = f2bf_rne(v.w * inv);
    *(ushort4*)(dst + tid * 4) = o4;
}

// ---------------- fused bf16 MFMA GEMM, depth-3 counted-vmcnt pipeline ------
// virtual A: rows 0..1023 = xb, rows 1024..2047 = wb[label[r]]
// B = wb, N = 10000 (pad 10240), K = 512
// m-tiles 0..7 write fea; tiles 8..15 clip/diag-zero/row-max -> atomicMax(s_u)
#define BM 128
#define BN 128
#define BK 32
#define NSTEP (D_ / BK)           // 16
#define NTILE_M 16
#define NTILE_N 79
#define NWG (NTILE_M * NTILE_N)   // 1264 = 8 * 158

__global__ __launch_bounds__(256) void mfma_gemm_kernel(
    const unsigned short* __restrict__ xb, const unsigned short* __restrict__ wb,
    const int* __restrict__ label,
    float* __restrict__ fea, unsigned* __restrict__ s_u) {
    __shared__ __align__(16) unsigned short As[3][BM * BK];   // 3 x 8 KB
    __shared__ __align__(16) unsigned short Bs[3][BM * BK];   // 3 x 8 KB

    const int tid = threadIdx.x;
    // bijective XCD swizzle (1264 % 8 == 0), m-tile fastest within each chunk
    const int orig = (blockIdx.x & 7) * (NWG / 8) + (blockIdx.x >> 3);
    const int m0 = (orig & 15) * BM;
    const int n0 = (orig >> 4) * BN;
    const bool feaTile = (m0 < B_);

    const int arow = tid >> 2;          // 0..63
    const int kc8 = (tid & 3) * 8;      // bf16 element offset along K
    const unsigned short* asrc[2];
    const unsigned short* bsrc[2];
    #pragma unroll
    for (int q = 0; q < 2; q++) {
        int rm = m0 + arow + q * 64;
        const unsigned short* ab;
        if (rm < B_) ab = xb + (size_t)rm * D_;
        else         ab = wb + (size_t)label[rm - B_] * D_;
        asrc[q] = ab + kc8;
        int rn = n0 + arow + q * 64;
        if (rn >= C_) rn = C_ - 1;
        bsrc[q] = wb + (size_t)rn * D_ + kc8;
    }

    const int lane = tid & 63;
    const int wv = tid >> 6;            // wave 0..3 -> 2x2 of 64x64
    const int wr = (wv >> 1) * 64;
    const int wc = (wv & 1) * 64;
    const int l15 = lane & 15;
    const int hi = lane >> 4;           // 0..3

    floatx4 acc[4][4];
    #pragma unroll
    for (int i = 0; i < 4; i++)
        #pragma unroll
        for (int j = 0; j < 4; j++)
            acc[i][j] = (floatx4){0.f, 0.f, 0.f, 0.f};

#define STAGE(buf, kt)                                                         \
    {                                                                          \
        _Pragma("unroll")                                                      \
        for (int q = 0; q < 2; q++) {                                          \
            __builtin_amdgcn_global_load_lds(                                  \
                (const __attribute__((address_space(1))) void*)(asrc[q] + (kt)),\
                (__attribute__((address_space(3))) void*)((char*)&As[buf][0] + tid * 16 + q * 4096), \
                16, 0, 0);                                                     \
            __builtin_amdgcn_global_load_lds(                                  \
                (const __attribute__((address_space(1))) void*)(bsrc[q] + (kt)),\
                (__attribute__((address_space(3))) void*)((char*)&Bs[buf][0] + tid * 16 + q * 4096), \
                16, 0, 0);                                                     \
        }                                                                      \
    }

    // prologue: stage steps 0..2 (12 VMEM instrs in flight per wave)
    STAGE(0, 0);
    STAGE(1, BK);
    STAGE(2, 2 * BK);

    #pragma unroll
    for (int t = 0; t < NSTEP; ++t) {
        // wait ONLY step t's 4 loads; keep the rest in flight across barriers
        if (t <= NSTEP - 3)      asm volatile("s_waitcnt vmcnt(8)" ::: "memory");
        else if (t == NSTEP - 2) asm volatile("s_waitcnt vmcnt(4)" ::: "memory");
        else                     asm volatile("s_waitcnt vmcnt(0)" ::: "memory");
        __builtin_amdgcn_s_barrier();
        __builtin_amdgcn_sched_barrier(0);

        const int buf = t % 3;
        short8 a[4], b[4];
        #pragma unroll
        for (int i = 0; i < 4; i++)
            a[i] = *(const short8*)&As[buf][(wr + i * 16 + l15) * BK + hi * 8];
        #pragma unroll
        for (int j = 0; j < 4; j++)
            b[j] = *(const short8*)&Bs[buf][(wc + j * 16 + l15) * BK + hi * 8];
        __builtin_amdgcn_s_setprio(1);
        #pragma unroll
        for (int i = 0; i < 4; i++)
            #pragma unroll
            for (int j = 0; j < 4; j++)
                acc[i][j] = __builtin_amdgcn_mfma_f32_16x16x32_bf16(
                    a[i], b[j], acc[i][j], 0, 0, 0);
        __builtin_amdgcn_s_setprio(0);

        __builtin_amdgcn_s_barrier();        // all waves done reading buf
        __builtin_amdgcn_sched_barrier(0);
        if (t + 3 < NSTEP) STAGE(buf, (t + 3) * BK);   // overwrite consumed buf
    }

    if (feaTile) {
        #pragma unroll
        for (int i = 0; i < 4; i++) {
            int m = m0 + wr + i * 16 + hi * 4;
            #pragma unroll
            for (int j = 0; j < 4; j++) {
                int n = n0 + wc + j * 16 + l15;
                if (n < C_) {
                    float* dst = fea + (size_t)m * C_ + n;
                    #pragma unroll
                    for (int r = 0; r < 4; r++)
                        dst[(size_t)r * C_] = acc[i][j][r];
                }
            }
        }
    } else {
        #pragma unroll
        for (int i = 0; i < 4; i++) {
            #pragma unroll
            for (int r = 0; r < 4; r++) {
                int row = wr + i * 16 + hi * 4 + r;    // 0..127 in tile
                int l = label[m0 - B_ + row];          // L1/L2-hot broadcast
                float vmax = -2.f;
                #pragma unroll
                for (int j = 0; j < 4; j++) {
                    int n = n0 + wc + j * 16 + l15;
                    float v = fminf(fmaxf(acc[i][j][r], -1.f), 1.f);
                    if (n == l) v = 0.f;               // diagonal zeroed
                    if (n < C_) vmax = fmaxf(vmax, v);
                }
                #pragma unroll
                for (int o = 8; o > 0; o >>= 1)
                    vmax = fmaxf(vmax, __shfl_xor(vmax, o, 64));
                if (l15 == 0) atomicMax(s_u + (m0 - B_ + row), enc_f(vmax));
            }
        }
    }
}

// ---------------- per-row logsumexp + softplus ----------------
__global__ __launch_bounds__(256) void row_lse_kernel(
    const float* __restrict__ fea, const float* __restrict__ cw,
    const int* __restrict__ label, float* __restrict__ sum_loss) {
    int row = blockIdx.x;
    int tid = threadIdx.x;
    const float* fr = fea + (size_t)row * C_;
    int l = label[row];
    float m = -1e30f, s = 0.f;
    for (int t = tid; t < C_ / 4; t += 256) {
        float4 f = *(const float4*)(fr + t * 4);
        float4 c = *(const float4*)(cw + t * 4);
        float vals[4] = { f.x + BETA * c.x, f.y + BETA * c.y,
                          f.z + BETA * c.z, f.w + BETA * c.w };
        int j0 = t * 4;
        #pragma unroll
        for (int e = 0; e < 4; e++) {
            if (j0 + e == l) continue;       // masked positive column
            float logit = GAMMA * vals[e];
            if (logit <= m) s += expf(logit - m);
            else { s = s * expf(m - logit) + 1.f; m = logit; }
        }
    }
    #pragma unroll
    for (int o = 32; o > 0; o >>= 1) {
        float om = __shfl_xor(m, o, 64);
        float os = __shfl_xor(s, o, 64);
        float nm = fmaxf(m, om);
        s = s * expf(m - nm) + os * expf(om - nm);
        m = nm;
    }
    __shared__ float red_m[4], red_s[4];
    if ((tid & 63) == 0) { red_m[tid >> 6] = m; red_s[tid >> 6] = s; }
    __syncthreads();
    if (tid == 0) {
        float M = red_m[0], S = red_s[0];
        #pragma unroll
        for (int wv = 1; wv < 4; wv++) {
            float om = red_m[wv], os = red_s[wv];
            float nm = fmaxf(M, om);
            S = S * expf(M - nm) + os * expf(om - nm);
            M = nm;
        }
        float sp = fr[l];                       // fea[row, label]
        float lse = M + logf(S) - GAMMA * sp;
        atomicAdd(sum_loss, softplus_f(lse));
    }
}

// ---------------- final scalar ----------------
__global__ __launch_bounds__(1024) void final_kernel(
    const unsigned* __restrict__ s_u, const float* __restrict__ sum_loss,
    float* __restrict__ out_loss) {
    int tid = threadIdx.x;
    float s = dec_f(s_u[tid]);
    #pragma unroll
    for (int o = 32; o > 0; o >>= 1) s += __shfl_xor(s, o, 64);
    __shared__ float red[16];
    if ((tid & 63) == 0) red[tid >> 6] = s;
    __syncthreads();
    if (tid == 0) {
        float tot = 0.f;
        #pragma unroll
        for (int wv = 0; wv < 16; wv++) tot += red[wv];
        float loss_w = softplus_f(tot / (float)B_ + 0.5f);
        *out_loss = *sum_loss / (float)B_ + LAMDA * loss_w;
    }
}

extern "C" void kernel_launch(void* const* d_in, const int* in_sizes, int n_in,
                              void* d_out, int out_size, void* d_ws, size_t ws_size,
                              hipStream_t stream) {
    const float* input  = (const float*)d_in[0];
    const float* weight = (const float*)d_in[1];
    const float* cw     = (const float*)d_in[2];
    const int*   label  = (const int*)d_in[3];
    float* out = (float*)d_out;

    char* ws = (char*)d_ws;
    unsigned short* xb = (unsigned short*)(ws + WS_XB);
    unsigned short* wb = (unsigned short*)(ws + WS_WB);
    unsigned* s_u      = (unsigned*)(ws + WS_SU);
    float*    sum_loss = (float*)(ws + WS_SUM);

    normcvt_kernel<<<B_ + C_, 128, 0, stream>>>(input, weight, xb, wb, s_u, sum_loss);

    mfma_gemm_kernel<<<NWG, 256, 0, stream>>>(xb, wb, label, out, s_u);

    row_lse_kernel<<<B_, 256, 0, stream>>>(out, cw, label, sum_loss);
    final_kernel<<<1, 1024, 0, stream>>>(s_u, sum_loss, out + (size_t)B_ * C_);
}

// Round 5
// 71.099 us; speedup vs baseline: 4.4322x; 1.1367x over previous
//
#include <hip/hip_runtime.h>
#include <math.h>

#define GAMMA 9.6f
#define BETA  0.83f
#define LAMDA 10.0f
#define B_ 1024
#define D_ 512
#define C_ 10000
#define M0_ 20.0f     // fixed logit shift: max possible gamma*(fea+beta*c) ~ 17.8

// ---- ws layout (bytes) ----
#define WS_XB   0
#define WS_WB   1048576
#define WS_SU   11288576   // s_u  [1024] u32
#define WS_T    11292672   // T    [1024] f32 (sum exp(gamma*(fea+beta*c)-M0), j != label)
#define WS_SP   11296768   // sp   [1024] f32 (fea[r, label_r])

typedef __attribute__((ext_vector_type(8))) short short8;
typedef __attribute__((ext_vector_type(4))) float floatx4;

__device__ __forceinline__ unsigned enc_f(float f) {
    unsigned i = __float_as_uint(f);
    return (i & 0x80000000u) ? ~i : (i | 0x80000000u);
}
__device__ __forceinline__ float dec_f(unsigned u) {
    return (u & 0x80000000u) ? __uint_as_float(u ^ 0x80000000u)
                             : __uint_as_float(~u);
}
__device__ __forceinline__ float softplus_f(float x) {
    return (x > 30.f) ? x : log1pf(expf(x));
}
__device__ __forceinline__ unsigned short f2bf_rne(float f) {
    unsigned u = __float_as_uint(f);
    u += 0x7FFFu + ((u >> 16) & 1u);
    return (unsigned short)(u >> 16);
}

// ---------------- normalize + convert to bf16 (+ fused init) ----------------
__global__ __launch_bounds__(128) void normcvt_kernel(
    const float* __restrict__ input, const float* __restrict__ weight,
    unsigned short* __restrict__ xb, unsigned short* __restrict__ wb,
    unsigned* __restrict__ s_u, float* __restrict__ T) {
    int row = blockIdx.x;
    int tid = threadIdx.x;
    if (row < B_ && tid == 0) { s_u[row] = 0u; T[row] = 0.f; }

    const float* src = (row < B_) ? (input + (size_t)row * D_)
                                  : (weight + (size_t)(row - B_) * D_);
    float4 v = *(const float4*)(src + tid * 4);
    float ss = v.x * v.x + v.y * v.y + v.z * v.z + v.w * v.w;
    #pragma unroll
    for (int o = 32; o > 0; o >>= 1) ss += __shfl_xor(ss, o, 64);
    __shared__ float red[2];
    if ((tid & 63) == 0) red[tid >> 6] = ss;
    __syncthreads();
    float inv = 1.0f / fmaxf(sqrtf(red[0] + red[1]), 1e-12f);
    unsigned short* dst = (row < B_) ? (xb + (size_t)row * D_)
                                     : (wb + (size_t)(row - B_) * D_);
    ushort4 o4;
    o4.x = f2bf_rne(v.x * inv);
    o4.y = f2bf_rne(v.y * inv);
    o4.z = f2bf_rne(v.z * inv);
    o4.w = f2bf_rne(v.w * inv);
    *(ushort4*)(dst + tid * 4) = o4;
}

// ---------------- fused bf16 MFMA GEMM (128x256 tile, 8 waves, 2-phase) -----
// virtual A: rows 0..1023 = xb, rows 1024..2047 = wb[label[r]]
// B = wb, N = 10000 (pad 10240), K = 512
// m-tiles 0..7: write fea + accumulate T_r, sp_r. tiles 8..15: row-max -> s_u
#define BM 128
#define BN 256
#define BK 32
#define NSTEP (D_ / BK)           // 16
#define NTILE_M 16
#define NTILE_N 40
#define NWG (NTILE_M * NTILE_N)   // 640 = 8 * 80

__global__ __launch_bounds__(512, 4) void mfma_gemm_kernel(
    const unsigned short* __restrict__ xb, const unsigned short* __restrict__ wb,
    const int* __restrict__ label, const float* __restrict__ cw,
    float* __restrict__ fea, unsigned* __restrict__ s_u,
    float* __restrict__ T, float* __restrict__ sp) {
    __shared__ __align__(16) unsigned short As[2][BM * BK];   // 2 x 8 KB
    __shared__ __align__(16) unsigned short Bs[2][BN * BK];   // 2 x 16 KB

    const int tid = threadIdx.x;
    // bijective XCD swizzle (640 % 8 == 0); m-tile fastest within each chunk
    const int orig = (blockIdx.x & 7) * (NWG / 8) + (blockIdx.x >> 3);
    const int m0 = (orig & 15) * BM;
    const int n0 = (orig >> 4) * BN;
    const bool feaTile = (m0 < B_);

    // staging: A 8KB -> 1 x 16B/thread; B 16KB -> 2 x 16B/thread
    const int srow = tid >> 2;          // 0..127
    const int kc8 = (tid & 3) * 8;      // bf16 element offset along K
    const unsigned short* asrc;
    {
        int rm = m0 + srow;
        if (rm < B_) asrc = xb + (size_t)rm * D_ + kc8;
        else         asrc = wb + (size_t)label[rm - B_] * D_ + kc8;
    }
    const unsigned short* bsrc[2];
    #pragma unroll
    for (int q = 0; q < 2; q++) {
        int rn = n0 + srow + q * 128;
        if (rn >= C_) rn = C_ - 1;
        bsrc[q] = wb + (size_t)rn * D_ + kc8;
    }

    const int lane = tid & 63;
    const int wv = tid >> 6;            // 0..7 -> 2(M) x 4(N)
    const int wvr = (wv >> 2) * 64;     // wave row origin: 0 or 64
    const int wvc = (wv & 3) * 64;      // wave col origin: 0,64,128,192
    const int l15 = lane & 15;
    const int hi = lane >> 4;           // 0..3

    floatx4 acc[4][4];
    #pragma unroll
    for (int i = 0; i < 4; i++)
        #pragma unroll
        for (int j = 0; j < 4; j++)
            acc[i][j] = (floatx4){0.f, 0.f, 0.f, 0.f};

#define STAGE(buf, kt)                                                         \
    {                                                                          \
        __builtin_amdgcn_global_load_lds(                                      \
            (const __attribute__((address_space(1))) void*)(asrc + (kt)),      \
            (__attribute__((address_space(3))) void*)((char*)&As[buf][0] + tid * 16), \
            16, 0, 0);                                                         \
        _Pragma("unroll")                                                      \
        for (int q = 0; q < 2; q++) {                                          \
            __builtin_amdgcn_global_load_lds(                                  \
                (const __attribute__((address_space(1))) void*)(bsrc[q] + (kt)),\
                (__attribute__((address_space(3))) void*)((char*)&Bs[buf][0] + tid * 16 + q * 8192), \
                16, 0, 0);                                                     \
        }                                                                      \
    }

    // prologue: stage K-step 0 into buf 0
    STAGE(0, 0);
    __syncthreads();

    int cur = 0;
    for (int t = 0; t < NSTEP; ++t) {
        int ktn = (t + 1) * BK;
        if (ktn < D_) STAGE(cur ^ 1, ktn);   // prefetch next step
        short8 a[4], b[4];
        #pragma unroll
        for (int i = 0; i < 4; i++)
            a[i] = *(const short8*)&As[cur][(wvr + i * 16 + l15) * BK + hi * 8];
        #pragma unroll
        for (int j = 0; j < 4; j++)
            b[j] = *(const short8*)&Bs[cur][(wvc + j * 16 + l15) * BK + hi * 8];
        #pragma unroll
        for (int i = 0; i < 4; i++)
            #pragma unroll
            for (int j = 0; j < 4; j++)
                acc[i][j] = __builtin_amdgcn_mfma_f32_16x16x32_bf16(
                    a[i], b[j], acc[i][j], 0, 0, 0);
        __syncthreads();   // drains vmcnt(0): prefetch landed; buf swap safe
        cur ^= 1;
    }

    if (feaTile) {
        // labels of my 16 rows (uniform across the 16-lane group -> L1 hot)
        int lbl_ir[4][4];
        #pragma unroll
        for (int i = 0; i < 4; i++)
            #pragma unroll
            for (int r = 0; r < 4; r++)
                lbl_ir[i][r] = label[m0 + wvr + i * 16 + hi * 4 + r];
        float cwj[4];
        #pragma unroll
        for (int j = 0; j < 4; j++) {
            int n = n0 + wvc + j * 16 + l15;
            cwj[j] = (n < C_) ? cw[n] : 0.f;
        }
        float rs[4][4];
        #pragma unroll
        for (int i = 0; i < 4; i++)
            #pragma unroll
            for (int r = 0; r < 4; r++) rs[i][r] = 0.f;

        #pragma unroll
        for (int i = 0; i < 4; i++) {
            #pragma unroll
            for (int j = 0; j < 4; j++) {
                int n = n0 + wvc + j * 16 + l15;
                if (n < C_) {
                    int m = m0 + wvr + i * 16 + hi * 4;
                    float* dst = fea + (size_t)m * C_ + n;
                    #pragma unroll
                    for (int r = 0; r < 4; r++) {
                        float v = acc[i][j][r];
                        dst[(size_t)r * C_] = v;
                        int l = lbl_ir[i][r];
                        if (n == l) sp[m + r] = v;
                        else rs[i][r] += expf(GAMMA * (v + BETA * cwj[j]) - M0_);
                    }
                }
            }
        }
        // 16-lane reduce + one atomicAdd per (i,r) row
        #pragma unroll
        for (int i = 0; i < 4; i++) {
            #pragma unroll
            for (int r = 0; r < 4; r++) {
                float s = rs[i][r];
                #pragma unroll
                for (int o = 8; o > 0; o >>= 1) s += __shfl_xor(s, o, 64);
                if (l15 == 0)
                    atomicAdd(T + (m0 + wvr + i * 16 + hi * 4 + r), s);
            }
        }
    } else {
        #pragma unroll
        for (int i = 0; i < 4; i++) {
            #pragma unroll
            for (int r = 0; r < 4; r++) {
                int row = m0 - B_ + wvr + i * 16 + hi * 4 + r;   // 0..1023
                int l = label[row];
                float vmax = -2.f;
                #pragma unroll
                for (int j = 0; j < 4; j++) {
                    int n = n0 + wvc + j * 16 + l15;
                    float v = fminf(fmaxf(acc[i][j][r], -1.f), 1.f);
                    if (n == l) v = 0.f;               // diagonal zeroed
                    if (n < C_) vmax = fmaxf(vmax, v);
                }
                #pragma unroll
                for (int o = 8; o > 0; o >>= 1)
                    vmax = fmaxf(vmax, __shfl_xor(vmax, o, 64));
                if (l15 == 0) atomicMax(s_u + row, enc_f(vmax));
            }
        }
    }
}

// ---------------- final scalar ----------------
__global__ __launch_bounds__(1024) void final_kernel(
    const unsigned* __restrict__ s_u, const float* __restrict__ T,
    const float* __restrict__ sp, float* __restrict__ out_loss) {
    int tid = threadIdx.x;
    float lse = M0_ + logf(T[tid]) - GAMMA * sp[tid];
    float lr = softplus_f(lse);
    float sv = dec_f(s_u[tid]);
    #pragma unroll
    for (int o = 32; o > 0; o >>= 1) {
        lr += __shfl_xor(lr, o, 64);
        sv += __shfl_xor(sv, o, 64);
    }
    __shared__ float red_l[16], red_s[16];
    if ((tid & 63) == 0) { red_l[tid >> 6] = lr; red_s[tid >> 6] = sv; }
    __syncthreads();
    if (tid == 0) {
        float tl = 0.f, ts = 0.f;
        #pragma unroll
        for (int wv = 0; wv < 16; wv++) { tl += red_l[wv]; ts += red_s[wv]; }
        float loss_w = softplus_f(ts / (float)B_ + 0.5f);
        *out_loss = tl / (float)B_ + LAMDA * loss_w;
    }
}

extern "C" void kernel_launch(void* const* d_in, const int* in_sizes, int n_in,
                              void* d_out, int out_size, void* d_ws, size_t ws_size,
                              hipStream_t stream) {
    const float* input  = (const float*)d_in[0];
    const float* weight = (const float*)d_in[1];
    const float* cw     = (const float*)d_in[2];
    const int*   label  = (const int*)d_in[3];
    float* out = (float*)d_out;

    char* ws = (char*)d_ws;
    unsigned short* xb = (unsigned short*)(ws + WS_XB);
    unsigned short* wb = (unsigned short*)(ws + WS_WB);
    unsigned* s_u      = (unsigned*)(ws + WS_SU);
    float*    T        = (float*)(ws + WS_T);
    float*    sp       = (float*)(ws + WS_SP);

    normcvt_kernel<<<B_ + C_, 128, 0, stream>>>(input, weight, xb, wb, s_u, T);

    mfma_gemm_kernel<<<NWG, 512, 0, stream>>>(xb, wb, label, cw, out, s_u, T, sp);

    final_kernel<<<1, 1024, 0, stream>>>(s_u, T, sp, out + (size_t)B_ * C_);
}